// Round 6
// baseline (192.676 us; speedup 1.0000x reference)
//
#include <hip/hip_runtime.h>

#define NTOK 32
#define PADT 1
#define MLEN 512
#define NLEN 1024
#define EPS_F 1e-7f
#define CCH  128
#define NC   8
#define NWAVE 4
#define NPHASE (NC + NWAVE - 1)   // 11
#define BSTRIDE 256

// Per-team LDS float offsets. Two teams (= two batches) per block.
// nl (bf16) is last in each team so negative stream underflow lands in the
// team's own scalar arrays and tail overrun lands in the next team / pad.
#define TOFF_P0   0        // P0s[1280] fp32 (row-0 prefix, padded for +199 overread)
#define TOFF_BND  1280     // bnd[4 ifaces][2 parity][BSTRIDE] fp32
#define TOFF_TOK  3328     // tok[512] int
#define TOFF_WT   3840     // wtmp[16] scan/count temps
#define TOFF_NL   3856     // nl bf16[32*1024] = 16384 float-words
#define TEAMF     20240
#define LDS_FLOATS (2 * TEAMF + 64)   // 40544 floats = 162,176 B <= 160 KiB

__device__ __forceinline__ float bf2f(ushort v) {
  return __uint_as_float(((unsigned)v) << 16);
}
__device__ __forceinline__ ushort f2bf(float x) {   // RNE, x positive finite
  unsigned u = __float_as_uint(x);
  unsigned r = u + 0x7FFFu + ((u >> 16) & 1u);
  return (ushort)(r >> 16);
}

// Round-2-proven systolic iteration (8 steps, 2 rows/lane, 1 col/step),
// streams changed to bf16 (sub0/sub1/ins) + fp32 (boundary).
template <bool MASKED>
__device__ __forceinline__ void do_iter(
    const ushort*& q0c, const ushort*& q1c, const ushort*& qic, const float*& qbc,
    float (&C0)[8], float (&C1)[8], float (&CI)[8], float (&CB)[8],
    float (&N0)[8], float (&N1)[8], float (&NI)[8], float (&NB)[8],
    float& dcur0, float& dcur1, float& diag0,
    int& sb, const int lane, float* __restrict__ bw)
{
  float wreg[8];
#pragma unroll
  for (int k = 0; k < 8; ++k) {
    N0[k] = bf2f(q0c[8 + k]); N1[k] = bf2f(q1c[8 + k]);
    NI[k] = bf2f(qic[8 + k]); NB[k] = qbc[8 + k];
  }
#pragma unroll
  for (int k = 0; k < 8; ++k) {
    float up0 = __int_as_float(__builtin_amdgcn_update_dpp(
        __float_as_int(CB[k]), __float_as_int(dcur1), 0x138, 0xF, 0xF, false));
    float a0 = diag0 + C0[k];      // substitute
    float b0 = up0 + 1.0f;         // delete
    float c0 = dcur0 + CI[k];      // insert
    float m0 = fminf(fminf(a0, b0), c0);
    float a1 = dcur0 + C1[k];
    float b1 = m0 + 1.0f;
    float c1 = dcur1 + CI[k];
    float m1 = fminf(fminf(a1, b1), c1);
    if (MASKED) {
      int rsk = sb + k - lane;
      bool act = ((unsigned)rsk) < (unsigned)CCH;
      diag0 = (rsk < CCH) ? up0 : diag0;
      dcur0 = act ? m0 : dcur0;
      dcur1 = act ? m1 : dcur1;
    } else {
      diag0 = up0; dcur0 = m0; dcur1 = m1;
    }
    wreg[k] = m1;
  }
  if (lane == 63) {
    int slot0 = sb - 63;
#pragma unroll
    for (int k = 0; k < 8; ++k) {
      int sl = slot0 + k;
      if (MASKED) sl = (sl < 0) ? 0 : sl;   // garbage pre-writes land on slot 0, overwritten later
      bw[sl] = wreg[k];
    }
  }
  q0c += 8; q1c += 8; qic += 8; qbc += 8; sb += 8;
}

__global__ __launch_bounds__(512, 1) void align_loss_kernel(
    const int* __restrict__ y_true, const float* __restrict__ y_pred,
    float* __restrict__ partial)
{
  extern __shared__ float smem[];
  const int t = threadIdx.x;
  const int lane = t & 63;
  const int team = t >> 8;        // 0 or 1
  const int tt = t & 255;         // team-local thread id
  const int tw = (t >> 6) & 3;    // team-local wave id

  float* sT   = smem + team * TEAMF;
  float* P0s  = sT + TOFF_P0;
  float* bnd  = sT + TOFF_BND;
  int*   tok  = (int*)(sT + TOFF_TOK);
  float* wtmp = sT + TOFF_WT;
  int*   wti  = (int*)wtmp;
  ushort* nlu = (ushort*)(sT + TOFF_NL);

  const int bb = blockIdx.x * 2 + team;   // batch index

  // ---- zero token buffer ----
  tok[tt] = 0; tok[tt + 256] = 0;
  __syncthreads();

  // ---- Phase A: left-shift compaction (2 halves of 256) ----
  int total = 0;
  for (int h = 0; h < 2; ++h) {
    int yt = y_true[bb * MLEN + h * 256 + tt];
    bool f = (yt != PADT);
    unsigned long long m = __ballot(f);
    int wp = __popcll(m & ((1ull << lane) - 1ull));
    if (lane == 0) wti[8 + tw] = __popcll(m);
    __syncthreads();
    int offs = total, ht = 0;
#pragma unroll
    for (int w2 = 0; w2 < NWAVE; ++w2) { int cnt = wti[8 + w2]; if (w2 < tw) offs += cnt; ht += cnt; }
    if (f) tok[offs + wp] = yt;
    total += ht;
    __syncthreads();
  }
  const int L = total;

  // ---- Phase B: nl[tk][r] = bf16(-log(clip(y_pred[bb,r,tk]/sum))) ----
  for (int r = tt; r < NLEN; r += 256) {
    const float4* rp = (const float4*)(y_pred + ((size_t)bb * NLEN + r) * NTOK);
    float4 q[8]; float s = 0.f;
#pragma unroll
    for (int u = 0; u < 8; ++u) { q[u] = rp[u]; s += q[u].x + q[u].y + q[u].z + q[u].w; }
    float inv = 1.0f / s;
#pragma unroll
    for (int u = 0; u < 8; ++u) {
      float pv[4] = {q[u].x, q[u].y, q[u].z, q[u].w};
#pragma unroll
      for (int c2 = 0; c2 < 4; ++c2) {
        float p = pv[c2] * inv;
        p = fminf(fmaxf(p, EPS_F), 1.0f - EPS_F);
        nlu[(u * 4 + c2) * NLEN + r] = f2bf(-__logf(p));
      }
    }
  }
  __syncthreads();

  // ---- Row-0 prefix: P0s[m] = D[0][m+1] = sum_{r<=m} ins[r] ----
  {
    const ushort4 iv4 = *(const ushort4*)(nlu + PADT * NLEN + 4 * tt);
    float i0 = bf2f(iv4.x), i1 = bf2f(iv4.y), i2 = bf2f(iv4.z), i3 = bf2f(iv4.w);
    float p1 = i0, p2 = i0 + i1, p3 = p2 + i2, s4 = p3 + i3;
    float x = s4;
#pragma unroll
    for (int d = 1; d < 64; d <<= 1) {
      float y = __shfl_up(x, d);
      if (lane >= d) x += y;
    }
    if (lane == 63) wtmp[tw] = x;
    __syncthreads();
    float pre = x - s4;
#pragma unroll
    for (int w2 = 0; w2 < NWAVE; ++w2) if (w2 < tw) pre += wtmp[w2];
    *(float4*)(P0s + 4 * tt) = make_float4(pre + p1, pre + p2, pre + p3, pre + s4);
  }

  // ---- DP state: lane owns rows r0 = 2tt+1, r1 = 2tt+2 ----
  const int r0 = 2 * tt + 1;
  const int tk0 = tok[2 * tt];
  const int tk1 = tok[2 * tt + 1];
  const ushort* sub0 = nlu + tk0 * NLEN;
  const ushort* sub1 = nlu + tk1 * NLEN;
  const ushort* insp = nlu + PADT * NLEN;
  float dcur0 = (float)r0;        // D[r0][0]
  float dcur1 = (float)(r0 + 1);  // D[r1][0]
  float diag0 = (float)(r0 - 1);  // D[r0-1][0]

  // ---- Systolic chunk phases ----
  for (int p = 0; p < NPHASE; ++p) {
    __syncthreads();
    const int c = p - tw;
    if (c < 0 || c >= NC) continue;
    const int base = c * CCH;
    const ushort* q0c = sub0 + base - lane;
    const ushort* q1c = sub1 + base - lane;
    const ushort* qic = insp + base - lane;
    const float* qbc = (tw == 0) ? (P0s + base)
                                 : (bnd + ((tw - 1) * 2 + (p & 1)) * BSTRIDE);
    float* bw = bnd + (tw * 2 + ((p + 1) & 1)) * BSTRIDE;  // tw==3 -> iface 3 (dead)

    float A0[8], A1[8], AI[8], AB[8], B0[8], B1[8], BI[8], BB[8];
#pragma unroll
    for (int k = 0; k < 8; ++k) {
      A0[k] = bf2f(q0c[k]); A1[k] = bf2f(q1c[k]);
      AI[k] = bf2f(qic[k]); AB[k] = qbc[k];
    }
    int sb = 0;
    for (int it2 = 0; it2 < 4; ++it2) {  // ramp-in (masked), sb 0..63
      do_iter<true>(q0c, q1c, qic, qbc, A0, A1, AI, AB, B0, B1, BI, BB, dcur0, dcur1, diag0, sb, lane, bw);
      do_iter<true>(q0c, q1c, qic, qbc, B0, B1, BI, BB, A0, A1, AI, AB, dcur0, dcur1, diag0, sb, lane, bw);
    }
    for (int it2 = 0; it2 < 4; ++it2) {  // clean middle, sb 64..127
      do_iter<false>(q0c, q1c, qic, qbc, A0, A1, AI, AB, B0, B1, BI, BB, dcur0, dcur1, diag0, sb, lane, bw);
      do_iter<false>(q0c, q1c, qic, qbc, B0, B1, BI, BB, A0, A1, AI, AB, dcur0, dcur1, diag0, sb, lane, bw);
    }
    for (int it2 = 0; it2 < 4; ++it2) {  // ramp-out (masked), sb 128..191
      do_iter<true>(q0c, q1c, qic, qbc, A0, A1, AI, AB, B0, B1, BI, BB, dcur0, dcur1, diag0, sb, lane, bw);
      do_iter<true>(q0c, q1c, qic, qbc, B0, B1, BI, BB, A0, A1, AI, AB, dcur0, dcur1, diag0, sb, lane, bw);
    }
  }

  // ---- Extract D[L][1024] ----
  if (r0 == L) partial[bb] = dcur0;
  if (r0 + 1 == L) partial[bb] = dcur1;
  if (L == 0 && tt == 0) partial[bb] = P0s[NLEN - 1];
}

__global__ void reduce_kernel(const float* __restrict__ partial, float* __restrict__ out) {
  if (threadIdx.x == 0) {
    float s = 0.f;
    for (int b2 = 0; b2 < 32; ++b2) s += partial[b2];
    out[0] = s;
  }
}

extern "C" void kernel_launch(void* const* d_in, const int* in_sizes, int n_in,
                              void* d_out, int out_size, void* d_ws, size_t ws_size,
                              hipStream_t stream) {
  const int*   y_true = (const int*)d_in[0];
  const float* y_pred = (const float*)d_in[1];
  float* out = (float*)d_out;
  float* partial = (float*)d_ws;

  const size_t lds_bytes = (size_t)LDS_FLOATS * sizeof(float);  // 162,176 B
  hipFuncSetAttribute((const void*)align_loss_kernel,
                      hipFuncAttributeMaxDynamicSharedMemorySize, (int)lds_bytes);

  hipLaunchKernelGGL(align_loss_kernel, dim3(16), dim3(512), lds_bytes, stream,
                     y_true, y_pred, partial);
  hipLaunchKernelGGL(reduce_kernel, dim3(1), dim3(64), 0, stream, partial, out);
}

// Round 7
// 95.943 us; speedup vs baseline: 2.0082x; 2.0082x over previous
//
#include <hip/hip_runtime.h>

#define NTOK 32
#define PADT 1
#define MLEN 512
#define NLEN 1024
#define EPS_F 1e-7f
#define CCH  128
#define NC   8
#define NWAVE 4
#define NPHASE (NC + NWAVE - 1)   // 11
#define BSTRIDE 256

// LDS float offsets
#define OFF_P0   0                      // P0s[1280] fp32 row-0 prefix (padded for +199 overread)
#define OFF_BND  1280                   // 7*256: ifaces 0..2 x 2 parity + dead buf for wave3
#define OFF_TOK  3072                   // tok[512] int
#define OFF_WT   3584                   // wtmp[16]
#define OFF_NLA  3600                   // bf16 A[32][1024] = 16384 float-words
#define OFF_NLB  19984                  // bf16 B[32][1024], B_u16[x] = A_u16[x+1] (shifted copy)
#define LDS_FLOATS (OFF_NLB + 16384 + 128)   // 36496 floats = 145,984 B

__device__ __forceinline__ float min3f(float a, float b, float c) {
  return fminf(fminf(a, b), c);
}
__device__ __forceinline__ float dpp_shr1(float old_v, float src) {
  return __int_as_float(__builtin_amdgcn_update_dpp(
      __float_as_int(old_v), __float_as_int(src), 0x138, 0xF, 0xF, false));
}
__device__ __forceinline__ ushort f2bf(float x) {   // RNE, x positive finite
  unsigned u = __float_as_uint(x);
  unsigned r = u + 0x7FFFu + ((u >> 16) & 1u);
  return (ushort)(r >> 16);
}

// R2-proven systolic iteration (8 slots, 2 rows/lane, 1 col/slot).
// Streams read as bf16 pairs (b32), boundary as fp32 pairs (b64),
// export as 2 aligned float4 via rolling regs. All loads consumed next call.
template <bool MASKED>
__device__ __forceinline__ void do_iter(
    const unsigned*& tp0, const unsigned*& tp1, const unsigned*& tpi,
    const float*& qbc,
    float (&C0)[8], float (&C1)[8], float (&CI)[8], float (&CB)[8],
    float (&N0)[8], float (&N1)[8], float (&NI)[8], float (&NB)[8],
    float& dcur0, float& dcur1, float& diag0,
    int& sb, const int lane, float* __restrict__ bw,
    float& wq0, float& wq1, float& wq2, float& wq3)
{
  // prefetch next 8 slots of all streams (pairs)
#pragma unroll
  for (int m = 0; m < 4; ++m) {
    unsigned u0 = tp0[4 + m];
    unsigned u1 = tp1[4 + m];
    unsigned ui = tpi[4 + m];
    N0[2*m] = __uint_as_float(u0 << 16);  N0[2*m+1] = __uint_as_float(u0 & 0xFFFF0000u);
    N1[2*m] = __uint_as_float(u1 << 16);  N1[2*m+1] = __uint_as_float(u1 & 0xFFFF0000u);
    NI[2*m] = __uint_as_float(ui << 16);  NI[2*m+1] = __uint_as_float(ui & 0xFFFF0000u);
    float2 vb = *(const float2*)(qbc + 8 + 2*m);
    NB[2*m] = vb.x; NB[2*m+1] = vb.y;
  }
#pragma unroll
  for (int k = 0; k < 8; ++k) {
    float up0 = dpp_shr1(CB[k], dcur1);           // V[r0-1][j] from lane-1 / boundary
    float m0 = min3f(diag0 + C0[k], up0 + 1.0f, dcur0 + CI[k]);
    float m1 = min3f(dcur0 + C1[k], m0 + 1.0f, dcur1 + CI[k]);
    if (MASKED) {
      int rsk = sb + k - lane;
      bool act = ((unsigned)rsk) < (unsigned)CCH;
      diag0 = (rsk < CCH) ? up0 : diag0;
      dcur0 = act ? m0 : dcur0;
      dcur1 = act ? m1 : dcur1;
    } else {
      diag0 = up0; dcur0 = m0; dcur1 = m1;
    }
    // rolling export regs: index == (lane63 slot q63) & 3 == (k+1)&3 (sb%8==0)
    switch ((k + 1) & 3) {
      case 0: wq0 = m1; break; case 1: wq1 = m1; break;
      case 2: wq2 = m1; break; case 3: wq3 = m1; break;
    }
    if (k == 2 || k == 6) {
      int q63 = sb + k - 63;
      if (lane == 63 && q63 >= 3 && q63 < 128)
        *(float4*)(bw + (q63 - 3)) = make_float4(wq0, wq1, wq2, wq3);
    }
  }
  tp0 += 4; tp1 += 4; tpi += 4; qbc += 8; sb += 8;
}

__global__ __launch_bounds__(256, 1) void align_loss_kernel(
    const int* __restrict__ y_true, const float* __restrict__ y_pred,
    float* __restrict__ partial)
{
  extern __shared__ float smem[];
  float* P0s  = smem + OFF_P0;
  float* bnd  = smem + OFF_BND;
  int*   tok  = (int*)(smem + OFF_TOK);
  float* wtmp = smem + OFF_WT;
  int*   wti  = (int*)wtmp;
  ushort* nlA = (ushort*)(smem + OFF_NLA);
  ushort* nlB = (ushort*)(smem + OFF_NLB);

  const int b = blockIdx.x;
  const int t = threadIdx.x;
  const int lane = t & 63;
  const int wv = t >> 6;

  // ---- zero token buffer ----
  tok[t] = 0; tok[t + 256] = 0;
  __syncthreads();

  // ---- Phase A: left-shift compaction (2 halves of 256) ----
  int total = 0;
  for (int h = 0; h < 2; ++h) {
    int yt = y_true[b * MLEN + h * 256 + t];
    bool f = (yt != PADT);
    unsigned long long m = __ballot(f);
    int wp = __popcll(m & ((1ull << lane) - 1ull));
    if (lane == 0) wti[8 + wv] = __popcll(m);
    __syncthreads();
    int offs = total, ht = 0;
#pragma unroll
    for (int w2 = 0; w2 < NWAVE; ++w2) { int cnt = wti[8 + w2]; if (w2 < wv) offs += cnt; ht += cnt; }
    if (f) tok[offs + wp] = yt;
    total += ht;
    __syncthreads();
  }
  const int L = total;

  // ---- Phase B: A[tk][r] = bf16(-log(clip(p))), B_u16[x] = A_u16[x+1] ----
  for (int r = t; r < NLEN; r += 256) {
    const float4* rp = (const float4*)(y_pred + ((size_t)b * NLEN + r) * NTOK);
    float4 q[8]; float s = 0.f;
#pragma unroll
    for (int u = 0; u < 8; ++u) { q[u] = rp[u]; s += q[u].x + q[u].y + q[u].z + q[u].w; }
    float inv = 1.0f / s;
#pragma unroll
    for (int u = 0; u < 8; ++u) {
      float pv[4] = {q[u].x, q[u].y, q[u].z, q[u].w};
#pragma unroll
      for (int c2 = 0; c2 < 4; ++c2) {
        float p = pv[c2] * inv;
        p = fminf(fmaxf(p, EPS_F), 1.0f - EPS_F);
        ushort v = f2bf(-__logf(p));
        int tk = u * 4 + c2;
        nlA[tk * 1024 + r] = v;
        if (r > 0) nlB[tk * 1024 + r - 1] = v;
      }
    }
  }
  __syncthreads();

  // ---- Row-0 prefix: P0s[m] = D[0][m+1] = sum_{r<=m} ins[r] ----
  {
    const ushort4 iv4 = *(const ushort4*)(nlA + PADT * 1024 + 4 * t);
    float i0v = __uint_as_float(((unsigned)iv4.x) << 16);
    float i1v = __uint_as_float(((unsigned)iv4.y) << 16);
    float i2v = __uint_as_float(((unsigned)iv4.z) << 16);
    float i3v = __uint_as_float(((unsigned)iv4.w) << 16);
    float p1 = i0v, p2 = i0v + i1v, p3 = p2 + i2v, s4 = p3 + i3v;
    float x = s4;
#pragma unroll
    for (int d = 1; d < 64; d <<= 1) {
      float y = __shfl_up(x, d);
      if (lane >= d) x += y;
    }
    if (lane == 63) wtmp[wv] = x;
    __syncthreads();
    float pre = x - s4;
#pragma unroll
    for (int w2 = 0; w2 < NWAVE; ++w2) if (w2 < wv) pre += wtmp[w2];
    *(float4*)(P0s + 4 * t) = make_float4(pre + p1, pre + p2, pre + p3, pre + s4);
  }

  // ---- DP state: lane owns rows r0 = 2t+1, r1 = 2t+2 ----
  const int r0 = 2 * t + 1;
  const int tk0 = tok[2 * t];
  const int tk1 = tok[2 * t + 1];
  float dcur0 = (float)r0;        // D[r0][0]
  float dcur1 = (float)(r0 + 1);  // D[r1][0]
  float diag0 = (float)(r0 - 1);  // D[r0-1][0]
  float wq0 = 0, wq1 = 0, wq2 = 0, wq3 = 0;

  const unsigned* baseA = (const unsigned*)nlA;   // u2 view: pair j = (A[2j], A[2j+1])
  const unsigned* baseB = (const unsigned*)nlB;   // pair j = (A[2j+1], A[2j+2])

  // ---- systolic chunk phases ----
  for (int p = 0; p < NPHASE; ++p) {
    __syncthreads();
    const int c = p - wv;
    if (c < 0 || c >= NC) continue;
    const int base = c * CCH;
    const int i0 = base - lane;          // absolute stream index at slot 0
    const int par = i0 & 1;
    const int joff = (i0 - par) >> 1;    // arithmetic shift = floor (i0-par even)
    const unsigned* tb = par ? baseB : baseA;
    const unsigned* tp0 = tb + tk0 * 512 + joff;
    const unsigned* tp1 = tb + tk1 * 512 + joff;
    const unsigned* tpi = tb + PADT * 512 + joff;
    const float* qbc = (wv == 0) ? (P0s + base)
                                 : (bnd + ((wv - 1) * 2 + (p & 1)) * BSTRIDE);
    float* bw = (wv < 3) ? (bnd + (wv * 2 + ((p + 1) & 1)) * BSTRIDE)
                         : (bnd + 6 * BSTRIDE);   // wave 3 -> dead buffer

    float A0[8], A1[8], AI[8], AB[8], B0[8], B1[8], BI[8], BB[8];
#pragma unroll
    for (int m = 0; m < 4; ++m) {         // prime slots 0..7
      unsigned u0 = tp0[m], u1 = tp1[m], ui = tpi[m];
      A0[2*m] = __uint_as_float(u0 << 16); A0[2*m+1] = __uint_as_float(u0 & 0xFFFF0000u);
      A1[2*m] = __uint_as_float(u1 << 16); A1[2*m+1] = __uint_as_float(u1 & 0xFFFF0000u);
      AI[2*m] = __uint_as_float(ui << 16); AI[2*m+1] = __uint_as_float(ui & 0xFFFF0000u);
      float2 vb = *(const float2*)(qbc + 2*m);
      AB[2*m] = vb.x; AB[2*m+1] = vb.y;
    }
    int sb = 0;
    for (int it2 = 0; it2 < 4; ++it2) {  // ramp-in (masked), sb 0..63
      do_iter<true>(tp0, tp1, tpi, qbc, A0, A1, AI, AB, B0, B1, BI, BB, dcur0, dcur1, diag0, sb, lane, bw, wq0, wq1, wq2, wq3);
      do_iter<true>(tp0, tp1, tpi, qbc, B0, B1, BI, BB, A0, A1, AI, AB, dcur0, dcur1, diag0, sb, lane, bw, wq0, wq1, wq2, wq3);
    }
    for (int it2 = 0; it2 < 4; ++it2) {  // clean middle, sb 64..127
      do_iter<false>(tp0, tp1, tpi, qbc, A0, A1, AI, AB, B0, B1, BI, BB, dcur0, dcur1, diag0, sb, lane, bw, wq0, wq1, wq2, wq3);
      do_iter<false>(tp0, tp1, tpi, qbc, B0, B1, BI, BB, A0, A1, AI, AB, dcur0, dcur1, diag0, sb, lane, bw, wq0, wq1, wq2, wq3);
    }
    for (int it2 = 0; it2 < 4; ++it2) {  // ramp-out (masked), sb 128..191
      do_iter<true>(tp0, tp1, tpi, qbc, A0, A1, AI, AB, B0, B1, BI, BB, dcur0, dcur1, diag0, sb, lane, bw, wq0, wq1, wq2, wq3);
      do_iter<true>(tp0, tp1, tpi, qbc, B0, B1, BI, BB, A0, A1, AI, AB, dcur0, dcur1, diag0, sb, lane, bw, wq0, wq1, wq2, wq3);
    }
  }

  // ---- extract D[L][1024] ----
  if (r0 == L) partial[b] = dcur0;
  if (r0 + 1 == L) partial[b] = dcur1;
  if (L == 0 && t == 0) partial[b] = P0s[NLEN - 1];
}

__global__ void reduce_kernel(const float* __restrict__ partial, float* __restrict__ out) {
  if (threadIdx.x == 0) {
    float s = 0.f;
    for (int b2 = 0; b2 < 32; ++b2) s += partial[b2];
    out[0] = s;
  }
}

extern "C" void kernel_launch(void* const* d_in, const int* in_sizes, int n_in,
                              void* d_out, int out_size, void* d_ws, size_t ws_size,
                              hipStream_t stream) {
  const int*   y_true = (const int*)d_in[0];
  const float* y_pred = (const float*)d_in[1];
  float* out = (float*)d_out;
  float* partial = (float*)d_ws;

  const size_t lds_bytes = (size_t)LDS_FLOATS * sizeof(float);   // 145,984 B
  hipFuncSetAttribute((const void*)align_loss_kernel,
                      hipFuncAttributeMaxDynamicSharedMemorySize, (int)lds_bytes);

  hipLaunchKernelGGL(align_loss_kernel, dim3(32), dim3(256), lds_bytes, stream,
                     y_true, y_pred, partial);
  hipLaunchKernelGGL(reduce_kernel, dim3(1), dim3(64), 0, stream, partial, out);
}